// Round 2
// baseline (3621.492 us; speedup 1.0000x reference)
//
#include <hip/hip_runtime.h>
#include <hip/hip_bf16.h>

// GestureCNNLSTM: conv1(1->16,3x3,p1)+relu+pool2 -> conv2(16->32,3x3,p1)+relu+pool2
//  -> flatten 192 -> gx GEMM (+b_ih+b_hh) -> 512-step LSTM (H=256) -> 64-dim classifier.
// Shapes: x [128][512][13][10] f32, out [128][64] f32.
// Intermediates feat/gx carried as f16 to keep d_ws usage at 159.4 MB.

typedef _Float16 half2v __attribute__((ext_vector_type(2)));

__device__ __forceinline__ float dot2f16(half2v a, half2v b, float c) {
#if defined(__has_builtin)
#if __has_builtin(__builtin_amdgcn_fdot2)
    return __builtin_amdgcn_fdot2(a, b, c, false);
#else
    return c + (float)a.x * (float)b.x + (float)a.y * (float)b.y;
#endif
#else
    return c + (float)a.x * (float)b.x + (float)a.y * (float)b.y;
#endif
}

// ---------------- Kernel A: fused conv1+pool1+conv2+pool2 ----------------
// 16384 blocks x 256 threads; wave w (64 lanes) handles image blockIdx.x*4+w.
__global__ __launch_bounds__(256) void conv_kernel(
    const float* __restrict__ x,     // [65536][13][10]
    const float* __restrict__ c1w,   // [16][1][3][3]
    const float* __restrict__ c1b,   // [16]
    const float* __restrict__ c2w,   // [32][16][3][3]
    const float* __restrict__ c2b,   // [32]
    _Float16* __restrict__ feat)     // [65536][192]
{
    __shared__ float w1t[9 * 16];        // [k][oc]
    __shared__ float b1s[16];
    __shared__ float w2t[16 * 9 * 32];   // [ic][k][oc]
    __shared__ float b2s[32];
    __shared__ float xp[4][14 * 12];     // padded input per image
    __shared__ float p1p[4][16 * 8 * 7]; // padded pool1 output per image

    const int tid = threadIdx.x;

    for (int idx = tid; idx < 144; idx += 256) {
        int oc = idx / 9, k = idx % 9;
        w1t[k * 16 + oc] = c1w[idx];
    }
    if (tid < 16) b1s[tid] = c1b[tid];
    for (int idx = tid; idx < 4608; idx += 256) {
        int oc = idx / 144, ic = (idx / 9) % 16, k = idx % 9;
        w2t[(ic * 9 + k) * 32 + oc] = c2w[idx];
    }
    if (tid < 32) b2s[tid] = c2b[tid];

    const int w = tid >> 6;
    const int lane = tid & 63;
    const int img = blockIdx.x * 4 + w;

    for (int i = lane; i < 14 * 12; i += 64) xp[w][i] = 0.f;
    for (int i = lane; i < 16 * 8 * 7; i += 64) p1p[w][i] = 0.f;
    __syncthreads();

    const float* xin = x + (size_t)img * 130;
    for (int i = lane; i < 130; i += 64) {
        int r = i / 10, c = i % 10;
        xp[w][(r + 1) * 12 + (c + 1)] = xin[i];
    }
    __syncthreads();

    // phase 1: conv1+relu+pool -> p1p interior. 480 outputs = 16oc x 30pos.
    {
        const int oc = lane & 15, q = lane >> 4;
        #pragma unroll
        for (int i = 0; i < 8; i++) {
            int pos = i * 4 + q;
            if (pos < 30) {
                int ph = pos / 5, pw = pos % 5;
                float cmax = -1e30f;
                #pragma unroll
                for (int pt = 0; pt < 4; pt++) {
                    int Y = 2 * ph + (pt >> 1), X = 2 * pw + (pt & 1);
                    float s = 0.f;
                    #pragma unroll
                    for (int k = 0; k < 9; k++) {
                        int dy = k / 3, dx = k % 3;
                        s += w1t[k * 16 + oc] * xp[w][(Y + dy) * 12 + X + dx];
                    }
                    cmax = fmaxf(cmax, s);
                }
                p1p[w][(oc * 8 + ph + 1) * 7 + (pw + 1)] = fmaxf(0.f, cmax + b1s[oc]);
            }
        }
    }
    __syncthreads();

    // phase 2: conv2+relu+pool -> feat. lane = oc(32) x pw2(2); 3 ph2 each.
    {
        const int oc = lane & 31, pw2 = lane >> 5;
        float acc[3][4];
        #pragma unroll
        for (int a = 0; a < 3; a++)
            #pragma unroll
            for (int b = 0; b < 4; b++) acc[a][b] = 0.f;

        for (int ic = 0; ic < 16; ic++) {
            #pragma unroll
            for (int k = 0; k < 9; k++) {
                int dy = k / 3, dx = k % 3;
                float wv = w2t[(ic * 9 + k) * 32 + oc];
                #pragma unroll
                for (int ph2 = 0; ph2 < 3; ph2++) {
                    #pragma unroll
                    for (int pt = 0; pt < 4; pt++) {
                        int y = 2 * ph2 + (pt >> 1) + dy;
                        int xx = 2 * pw2 + (pt & 1) + dx;
                        acc[ph2][pt] += wv * p1p[w][(ic * 8 + y) * 7 + xx];
                    }
                }
            }
        }
        float bias = b2s[oc];
        _Float16* fo = feat + (size_t)img * 192;
        #pragma unroll
        for (int ph2 = 0; ph2 < 3; ph2++) {
            float m = fmaxf(fmaxf(acc[ph2][0], acc[ph2][1]),
                            fmaxf(acc[ph2][2], acc[ph2][3]));
            fo[oc * 6 + ph2 * 2 + pw2] = (_Float16)fmaxf(0.f, m + bias);
        }
    }
}

// ---------------- Kernel B: gx = feat @ W_ih^T + b_ih + b_hh ----------------
// M=65536, N=1024, K=192. grid (1024, 16) x 256 thr; 64x64 tile, 4x4 micro.
__global__ __launch_bounds__(256) void gemm_gx_kernel(
    const _Float16* __restrict__ feat,  // [65536][192]
    const float* __restrict__ Wih,      // [1024][192]
    const float* __restrict__ bih,
    const float* __restrict__ bhh,
    _Float16* __restrict__ gx)          // [65536][1024]
{
    __shared__ float As[64][64];
    __shared__ float Bs[64][65];
    const int tid = threadIdx.x;
    const int m0 = blockIdx.x * 64;
    const int n0 = blockIdx.y * 64;
    const int tx = tid & 15, ty = tid >> 4;
    float acc[4][4] = {};

    for (int k0 = 0; k0 < 192; k0 += 64) {
        __syncthreads();
        #pragma unroll
        for (int it = 0; it < 16; it++) {
            int idx = tid + it * 256;
            int r = idx >> 6, c = idx & 63;
            As[r][c] = (float)feat[(size_t)(m0 + r) * 192 + k0 + c];
            Bs[c][r] = Wih[(size_t)(n0 + r) * 192 + k0 + c];
        }
        __syncthreads();
        for (int kk = 0; kk < 64; kk++) {
            float a[4], b[4];
            #pragma unroll
            for (int i = 0; i < 4; i++) a[i] = As[ty * 4 + i][kk];
            #pragma unroll
            for (int j = 0; j < 4; j++) b[j] = Bs[kk][tx * 4 + j];
            #pragma unroll
            for (int i = 0; i < 4; i++)
                #pragma unroll
                for (int j = 0; j < 4; j++)
                    acc[i][j] += a[i] * b[j];
        }
    }
    // packed 8B f16 stores: 4 consecutive n per row
    #pragma unroll
    for (int i = 0; i < 4; i++) {
        union { _Float16 h[4]; uint2 u; } pk;
        #pragma unroll
        for (int j = 0; j < 4; j++) {
            int n = n0 + tx * 4 + j;
            pk.h[j] = (_Float16)(acc[i][j] + bih[n] + bhh[n]);
        }
        *(uint2*)&gx[(size_t)(m0 + ty * 4 + i) * 1024 + n0 + tx * 4] = pk.u;
    }
}

// ---------------- Kernel C: 512-step LSTM + classifier ----------------
// 128 blocks (one per batch element) x 256 threads. Thread t owns gate rows
// {t, t+256, t+512, t+768} (i,f,g,o for hidden index t) -> no gate exchange.
// W_hh cached as packed f16: k 0..191 in regs (4x96 half2 = 384 VGPR),
// k 192..255 in LDS (128 KB, XOR-swizzled). h kept in LDS as f16 (dbl-buffered).
__global__ __launch_bounds__(256, 1) void lstm_kernel(
    const _Float16* __restrict__ gx, // [128][512][1024]
    const float* __restrict__ Whh,   // [1024][256]
    const float* __restrict__ clsw,  // [64][256]
    const float* __restrict__ clsb,  // [64]
    float* __restrict__ out)         // [128][64]
{
    __shared__ unsigned int wl[1024 * 32];  // packed half2, pairs 96..127 per row
    __shared__ _Float16 hbuf[2][256];
    __shared__ float hfin[256];

    const int t = threadIdx.x;
    const int b = blockIdx.x;
    const int sw = t & 31;  // same for all 4 rows (256 % 32 == 0)

    // register-resident weights, pairs 0..95
    half2v wr[4][96];
    #pragma unroll
    for (int g = 0; g < 4; g++) {
        const float* wrow = Whh + (size_t)(t + 256 * g) * 256;
        #pragma unroll
        for (int p = 0; p < 96; p++) {
            float2 w2 = *(const float2*)&wrow[2 * p];
            half2v hv;
            hv.x = (_Float16)w2.x;
            hv.y = (_Float16)w2.y;
            wr[g][p] = hv;
        }
    }
    // LDS-resident tail, pairs 96..127, swizzled so reads are ~conflict-free
    for (int g = 0; g < 4; g++) {
        int row = t + 256 * g;
        const float* wrow = Whh + (size_t)row * 256;
        for (int p = 0; p < 32; p++) {
            float2 w2 = *(const float2*)&wrow[192 + 2 * p];
            half2v hv;
            hv.x = (_Float16)w2.x;
            hv.y = (_Float16)w2.y;
            wl[row * 32 + (p ^ sw)] = __builtin_bit_cast(unsigned int, hv);
        }
    }
    hbuf[0][t] = (_Float16)0.f;
    __syncthreads();

    float c = 0.f;
    int cur = 0;
    const _Float16* gxb = gx + (size_t)b * 512 * 1024;
    const unsigned int* wl0 = wl + (size_t)t * 32;

    for (int step = 0; step < 512; step++) {
        const _Float16* gxt = gxb + (size_t)step * 1024;
        float acc0 = (float)gxt[t];
        float acc1 = (float)gxt[t + 256];
        float acc2 = (float)gxt[t + 512];
        float acc3 = (float)gxt[t + 768];

        const _Float16* hrow = &hbuf[cur][0];
        #pragma unroll
        for (int p = 0; p < 96; p++) {
            half2v hv = *(const half2v*)&hrow[2 * p];
            acc0 = dot2f16(wr[0][p], hv, acc0);
            acc1 = dot2f16(wr[1][p], hv, acc1);
            acc2 = dot2f16(wr[2][p], hv, acc2);
            acc3 = dot2f16(wr[3][p], hv, acc3);
        }
        #pragma unroll
        for (int p = 0; p < 32; p++) {
            half2v hv = *(const half2v*)&hrow[192 + 2 * p];
            int off = (p ^ sw);
            acc0 = dot2f16(__builtin_bit_cast(half2v, wl0[off]), hv, acc0);
            acc1 = dot2f16(__builtin_bit_cast(half2v, wl0[256 * 32 + off]), hv, acc1);
            acc2 = dot2f16(__builtin_bit_cast(half2v, wl0[512 * 32 + off]), hv, acc2);
            acc3 = dot2f16(__builtin_bit_cast(half2v, wl0[768 * 32 + off]), hv, acc3);
        }

        float i_ = 1.f / (1.f + __expf(-acc0));
        float f_ = 1.f / (1.f + __expf(-acc1));
        float g_ = 1.f - 2.f / (__expf(2.f * acc2) + 1.f);
        float o_ = 1.f / (1.f + __expf(-acc3));
        c = f_ * c + i_ * g_;
        float th = 1.f - 2.f / (__expf(2.f * c) + 1.f);
        float h = o_ * th;
        hbuf[cur ^ 1][t] = (_Float16)h;
        if (step == 511) hfin[t] = h;
        __syncthreads();
        cur ^= 1;
    }

    if (t < 64) {
        const float* wrow = clsw + t * 256;
        float s = clsb[t];
        for (int k = 0; k < 256; k++) s += wrow[k] * hfin[k];
        out[b * 64 + t] = s;
    }
}

extern "C" void kernel_launch(void* const* d_in, const int* in_sizes, int n_in,
                              void* d_out, int out_size, void* d_ws, size_t ws_size,
                              hipStream_t stream) {
    const float* x    = (const float*)d_in[0];
    const float* c1w  = (const float*)d_in[1];
    const float* c1b  = (const float*)d_in[2];
    const float* c2w  = (const float*)d_in[3];
    const float* c2b  = (const float*)d_in[4];
    const float* Wih  = (const float*)d_in[5];
    const float* bih  = (const float*)d_in[6];
    const float* Whh  = (const float*)d_in[7];
    const float* bhh  = (const float*)d_in[8];
    const float* clsw = (const float*)d_in[9];
    const float* clsb = (const float*)d_in[10];

    _Float16* feat = (_Float16*)d_ws;                   // 65536*192*2B = 25.2 MB
    _Float16* gx   = feat + (size_t)65536 * 192;        // 65536*1024*2B = 134.2 MB
    float* outp = (float*)d_out;

    hipLaunchKernelGGL(conv_kernel, dim3(16384), dim3(256), 0, stream,
                       x, c1w, c1b, c2w, c2b, feat);
    hipLaunchKernelGGL(gemm_gx_kernel, dim3(1024, 16), dim3(256), 0, stream,
                       feat, Wih, bih, bhh, gx);
    hipLaunchKernelGGL(lstm_kernel, dim3(128), dim3(256), 0, stream,
                       gx, Whh, clsw, clsb, outp);
}

// Round 3
// 1685.445 us; speedup vs baseline: 2.1487x; 2.1487x over previous
//
#include <hip/hip_runtime.h>
#include <hip/hip_bf16.h>

// GestureCNNLSTM: conv1(1->16,3x3,p1)+relu+pool2 -> conv2(16->32,3x3,p1)+relu+pool2
//  -> flatten 192 -> gx GEMM (+b_ih+b_hh) -> 512-step LSTM (H=256) -> 64-dim classifier.
// x [128][512][13][10] f32, out [128][64] f32. feat/gx carried as f16 (159.4 MB ws).

typedef _Float16 half2v __attribute__((ext_vector_type(2)));

__device__ __forceinline__ float dot2f16(half2v a, half2v b, float c) {
#if defined(__has_builtin)
#if __has_builtin(__builtin_amdgcn_fdot2)
    return __builtin_amdgcn_fdot2(a, b, c, false);
#else
    return c + (float)a.x * (float)b.x + (float)a.y * (float)b.y;
#endif
#else
    return c + (float)a.x * (float)b.x + (float)a.y * (float)b.y;
#endif
}

__device__ __forceinline__ unsigned int packf2(const float* p) {
    half2v hv;
    hv.x = (_Float16)p[0];
    hv.y = (_Float16)p[1];
    return __builtin_bit_cast(unsigned int, hv);
}

// ---------------- Kernel A: fused conv1+pool1+conv2+pool2 ----------------
__global__ __launch_bounds__(256) void conv_kernel(
    const float* __restrict__ x,     // [65536][13][10]
    const float* __restrict__ c1w,   // [16][1][3][3]
    const float* __restrict__ c1b,   // [16]
    const float* __restrict__ c2w,   // [32][16][3][3]
    const float* __restrict__ c2b,   // [32]
    _Float16* __restrict__ feat)     // [65536][192]
{
    __shared__ float w1t[9 * 16];
    __shared__ float b1s[16];
    __shared__ float w2t[16 * 9 * 32];
    __shared__ float b2s[32];
    __shared__ float xp[4][14 * 12];
    __shared__ float p1p[4][16 * 8 * 7];

    const int tid = threadIdx.x;

    for (int idx = tid; idx < 144; idx += 256) {
        int oc = idx / 9, k = idx % 9;
        w1t[k * 16 + oc] = c1w[idx];
    }
    if (tid < 16) b1s[tid] = c1b[tid];
    for (int idx = tid; idx < 4608; idx += 256) {
        int oc = idx / 144, ic = (idx / 9) % 16, k = idx % 9;
        w2t[(ic * 9 + k) * 32 + oc] = c2w[idx];
    }
    if (tid < 32) b2s[tid] = c2b[tid];

    const int w = tid >> 6;
    const int lane = tid & 63;
    const int img = blockIdx.x * 4 + w;

    for (int i = lane; i < 14 * 12; i += 64) xp[w][i] = 0.f;
    for (int i = lane; i < 16 * 8 * 7; i += 64) p1p[w][i] = 0.f;
    __syncthreads();

    const float* xin = x + (size_t)img * 130;
    for (int i = lane; i < 130; i += 64) {
        int r = i / 10, c = i % 10;
        xp[w][(r + 1) * 12 + (c + 1)] = xin[i];
    }
    __syncthreads();

    {
        const int oc = lane & 15, q = lane >> 4;
        #pragma unroll
        for (int i = 0; i < 8; i++) {
            int pos = i * 4 + q;
            if (pos < 30) {
                int ph = pos / 5, pw = pos % 5;
                float cmax = -1e30f;
                #pragma unroll
                for (int pt = 0; pt < 4; pt++) {
                    int Y = 2 * ph + (pt >> 1), X = 2 * pw + (pt & 1);
                    float s = 0.f;
                    #pragma unroll
                    for (int k = 0; k < 9; k++) {
                        int dy = k / 3, dx = k % 3;
                        s += w1t[k * 16 + oc] * xp[w][(Y + dy) * 12 + X + dx];
                    }
                    cmax = fmaxf(cmax, s);
                }
                p1p[w][(oc * 8 + ph + 1) * 7 + (pw + 1)] = fmaxf(0.f, cmax + b1s[oc]);
            }
        }
    }
    __syncthreads();

    {
        const int oc = lane & 31, pw2 = lane >> 5;
        float acc[3][4];
        #pragma unroll
        for (int a = 0; a < 3; a++)
            #pragma unroll
            for (int b = 0; b < 4; b++) acc[a][b] = 0.f;

        for (int ic = 0; ic < 16; ic++) {
            #pragma unroll
            for (int k = 0; k < 9; k++) {
                int dy = k / 3, dx = k % 3;
                float wv = w2t[(ic * 9 + k) * 32 + oc];
                #pragma unroll
                for (int ph2 = 0; ph2 < 3; ph2++) {
                    #pragma unroll
                    for (int pt = 0; pt < 4; pt++) {
                        int y = 2 * ph2 + (pt >> 1) + dy;
                        int xx = 2 * pw2 + (pt & 1) + dx;
                        acc[ph2][pt] += wv * p1p[w][(ic * 8 + y) * 7 + xx];
                    }
                }
            }
        }
        float bias = b2s[oc];
        _Float16* fo = feat + (size_t)img * 192;
        #pragma unroll
        for (int ph2 = 0; ph2 < 3; ph2++) {
            float m = fmaxf(fmaxf(acc[ph2][0], acc[ph2][1]),
                            fmaxf(acc[ph2][2], acc[ph2][3]));
            fo[oc * 6 + ph2 * 2 + pw2] = (_Float16)fmaxf(0.f, m + bias);
        }
    }
}

// ---------------- Kernel B: gx = feat @ W_ih^T + b_ih + b_hh (f16 dot2) ----------
// M=65536, N=1024, K=192 (96 half2 pairs). Tile 64Mx128N, 256 thr, micro 4x8.
// As[k2][m] (broadcast reads), Bs[k2][sigma(n)] with sigma(n)=(n&7)*16+(n>>3)
// so inner-loop b-reads land on 16 distinct banks. All K staged at once (72 KB).
__global__ __launch_bounds__(256) void gemm_gx_kernel(
    const _Float16* __restrict__ feat,  // [65536][192]
    const float* __restrict__ Wih,      // [1024][192]
    const float* __restrict__ bih,
    const float* __restrict__ bhh,
    _Float16* __restrict__ gx)          // [65536][1024]
{
    __shared__ unsigned int As[96][64];    // 24 KB
    __shared__ unsigned int Bs[96][128];   // 48 KB
    const int tid = threadIdx.x;
    const int m0 = blockIdx.x * 64;
    const int n0 = blockIdx.y * 128;

    // stage As: 64 rows x 24 uint4 (coalesced global, conflicted LDS write once)
    #pragma unroll
    for (int it = 0; it < 6; it++) {
        int q = tid + it * 256;          // 0..1535
        int m = q / 24, p4 = q % 24;
        uint4 v = *(const uint4*)(feat + (size_t)(m0 + m) * 192 + p4 * 8);
        As[p4 * 4 + 0][m] = v.x;
        As[p4 * 4 + 1][m] = v.y;
        As[p4 * 4 + 2][m] = v.z;
        As[p4 * 4 + 3][m] = v.w;
    }
    // stage Bs: p = q>>7, n = q&127 -> swizzled store
    #pragma unroll
    for (int it = 0; it < 48; it++) {
        int q = tid + it * 256;          // 0..12287
        int p = q >> 7, n = q & 127;
        float2 w2 = *(const float2*)(Wih + (size_t)(n0 + n) * 192 + 2 * p);
        half2v hv;
        hv.x = (_Float16)w2.x;
        hv.y = (_Float16)w2.y;
        Bs[p][((n & 7) << 4) | (n >> 3)] = __builtin_bit_cast(unsigned int, hv);
    }
    __syncthreads();

    const int tx = tid & 15, ty = tid >> 4;
    float acc[4][8] = {};
    for (int k2 = 0; k2 < 96; k2++) {
        half2v a[4], bb[8];
        #pragma unroll
        for (int i = 0; i < 4; i++)
            a[i] = __builtin_bit_cast(half2v, As[k2][ty * 4 + i]);
        #pragma unroll
        for (int j = 0; j < 8; j++)
            bb[j] = __builtin_bit_cast(half2v, Bs[k2][j * 16 + tx]);  // sigma(tx*8+j)
        #pragma unroll
        for (int i = 0; i < 4; i++)
            #pragma unroll
            for (int j = 0; j < 8; j++)
                acc[i][j] = dot2f16(a[i], bb[j], acc[i][j]);
    }

    #pragma unroll
    for (int i = 0; i < 4; i++) {
        int m = m0 + ty * 4 + i;
        union { _Float16 h[8]; uint4 u; } pk;
        #pragma unroll
        for (int j = 0; j < 8; j++) {
            int n = n0 + tx * 8 + j;
            pk.h[j] = (_Float16)(acc[i][j] + bih[n] + bhh[n]);
        }
        *(uint4*)&gx[(size_t)m * 1024 + n0 + tx * 8] = pk.u;
    }
}

// ---------------- Kernel C: 512-step LSTM + classifier ----------------
// 128 blocks x 512 threads. Thread t owns gate rows r0=t, r1=t+512:
//   t<256:  (i_j, g_j) j=t;  t>=256: (f_j, o_j) j=t-256  -> one LDS exchange.
// W_hh f16: pairs 0..91 in regs (2x92=184 VGPR), pairs 92..127 in LDS [pair][row]
// (consecutive-lane reads, conflict-free). h broadcast-read as uniform uint4.
__global__ __launch_bounds__(512, 1) void lstm_kernel(
    const _Float16* __restrict__ gx, // [128][512][1024]
    const float* __restrict__ Whh,   // [1024][256]
    const float* __restrict__ clsw,  // [64][256]
    const float* __restrict__ clsb,  // [64]
    float* __restrict__ out)         // [128][64]
{
    __shared__ unsigned int wlds[36 * 1024];           // 144 KB: [q][row]
    __shared__ __align__(16) _Float16 hbuf[2][256];    // 1 KB
    __shared__ float hfin[256];                        // 1 KB
    __shared__ float xg[512];                          // 2 KB (f, o exchange)

    const int t = threadIdx.x;
    const int b = blockIdx.x;
    const int r0 = t, r1 = t + 512;

    const float* w0 = Whh + (size_t)r0 * 256;
    const float* w1 = Whh + (size_t)r1 * 256;

    half2v wr0[92], wr1[92];
    #pragma unroll
    for (int p = 0; p < 92; p++) {
        wr0[p] = __builtin_bit_cast(half2v, packf2(&w0[2 * p]));
        wr1[p] = __builtin_bit_cast(half2v, packf2(&w1[2 * p]));
    }
    #pragma unroll
    for (int q = 0; q < 36; q++) {
        wlds[q * 1024 + r0] = packf2(&w0[184 + 2 * q]);
        wlds[q * 1024 + r1] = packf2(&w1[184 + 2 * q]);
    }
    if (t < 256) hbuf[0][t] = (_Float16)0.f;
    __syncthreads();

    float c = 0.f;
    int cur = 0;
    const _Float16* gxb = gx + (size_t)b * 512 * 1024;
    float ga = (float)gxb[r0];
    float gb = (float)gxb[r1];

    for (int step = 0; step < 512; step++) {
        // prefetch next step's gx (step 511 re-reads step 0 harmlessly)
        const _Float16* gxn = gxb + (size_t)((step + 1) & 511) * 1024;
        _Float16 na = gxn[r0];
        _Float16 nb = gxn[r1];

        float acc0 = ga, acc1 = gb;
        const unsigned int* hp = (const unsigned int*)&hbuf[cur][0];

        // register-resident pairs 0..91 (h[0..183]); uniform uint4 h loads
        #pragma unroll
        for (int ch = 0; ch < 23; ch++) {
            uint4 hv = *(const uint4*)(hp + ch * 4);
            unsigned int hw[4] = {hv.x, hv.y, hv.z, hv.w};
            #pragma unroll
            for (int j = 0; j < 4; j++) {
                half2v h2 = __builtin_bit_cast(half2v, hw[j]);
                acc0 = dot2f16(wr0[ch * 4 + j], h2, acc0);
                acc1 = dot2f16(wr1[ch * 4 + j], h2, acc1);
            }
        }
        // LDS-resident pairs 92..127 (h[184..255])
        #pragma unroll
        for (int ch = 0; ch < 9; ch++) {
            uint4 hv = *(const uint4*)(hp + 92 + ch * 4);
            unsigned int hw[4] = {hv.x, hv.y, hv.z, hv.w};
            #pragma unroll
            for (int j = 0; j < 4; j++) {
                int q = ch * 4 + j;
                half2v h2 = __builtin_bit_cast(half2v, hw[j]);
                acc0 = dot2f16(__builtin_bit_cast(half2v, wlds[q * 1024 + r0]), h2, acc0);
                acc1 = dot2f16(__builtin_bit_cast(half2v, wlds[q * 1024 + r1]), h2, acc1);
            }
        }

        if (t >= 256) {           // acc0 = f_j, acc1 = o_j for j = t-256
            xg[t - 256] = acc0;
            xg[t] = acc1;         // t = 256 + j -> slot 256+j
        }
        __syncthreads();
        if (t < 256) {            // acc0 = i_j, acc1 = g_j for j = t
            float i_ = 1.f / (1.f + __expf(-acc0));
            float g_ = 1.f - 2.f / (__expf(2.f * acc1) + 1.f);
            float f_ = 1.f / (1.f + __expf(-xg[t]));
            float o_ = 1.f / (1.f + __expf(-xg[t + 256]));
            c = f_ * c + i_ * g_;
            float th = 1.f - 2.f / (__expf(2.f * c) + 1.f);
            float h = o_ * th;
            hbuf[cur ^ 1][t] = (_Float16)h;
            if (step == 511) hfin[t] = h;
        }
        __syncthreads();
        cur ^= 1;
        ga = (float)na;
        gb = (float)nb;
    }

    if (t < 64) {
        const float* wrow = clsw + t * 256;
        float s = clsb[t];
        for (int k = 0; k < 256; k++) s += wrow[k] * hfin[k];
        out[b * 64 + t] = s;
    }
}

extern "C" void kernel_launch(void* const* d_in, const int* in_sizes, int n_in,
                              void* d_out, int out_size, void* d_ws, size_t ws_size,
                              hipStream_t stream) {
    const float* x    = (const float*)d_in[0];
    const float* c1w  = (const float*)d_in[1];
    const float* c1b  = (const float*)d_in[2];
    const float* c2w  = (const float*)d_in[3];
    const float* c2b  = (const float*)d_in[4];
    const float* Wih  = (const float*)d_in[5];
    const float* bih  = (const float*)d_in[6];
    const float* Whh  = (const float*)d_in[7];
    const float* bhh  = (const float*)d_in[8];
    const float* clsw = (const float*)d_in[9];
    const float* clsb = (const float*)d_in[10];

    _Float16* feat = (_Float16*)d_ws;                   // 65536*192*2B = 25.2 MB
    _Float16* gx   = feat + (size_t)65536 * 192;        // 65536*1024*2B = 134.2 MB
    float* outp = (float*)d_out;

    hipLaunchKernelGGL(conv_kernel, dim3(16384), dim3(256), 0, stream,
                       x, c1w, c1b, c2w, c2b, feat);
    hipLaunchKernelGGL(gemm_gx_kernel, dim3(1024, 8), dim3(256), 0, stream,
                       feat, Wih, bih, bhh, gx);
    hipLaunchKernelGGL(lstm_kernel, dim3(128), dim3(512), 0, stream,
                       gx, Whh, clsw, clsb, outp);
}

// Round 4
// 1328.506 us; speedup vs baseline: 2.7260x; 1.2687x over previous
//
#include <hip/hip_runtime.h>
#include <hip/hip_bf16.h>

// GestureCNNLSTM: conv1(1->16,3x3,p1)+relu+pool2 -> conv2(16->32,3x3,p1)+relu+pool2
//  -> flatten 192 -> gx GEMM (+b_ih+b_hh) -> 512-step LSTM (H=256) -> 64-dim classifier.
// x [128][512][13][10] f32, out [128][64] f32. feat/gx carried as f16 (159.4 MB ws).

typedef _Float16 half2v __attribute__((ext_vector_type(2)));
typedef _Float16 f16x8 __attribute__((ext_vector_type(8)));
typedef float f32x4 __attribute__((ext_vector_type(4)));

__device__ __forceinline__ float dot2f16(half2v a, half2v b, float c) {
#if defined(__has_builtin)
#if __has_builtin(__builtin_amdgcn_fdot2)
    return __builtin_amdgcn_fdot2(a, b, c, false);
#else
    return c + (float)a.x * (float)b.x + (float)a.y * (float)b.y;
#endif
#else
    return c + (float)a.x * (float)b.x + (float)a.y * (float)b.y;
#endif
}

__device__ __forceinline__ unsigned int packf2(const float* p) {
    half2v hv;
    hv.x = (_Float16)p[0];
    hv.y = (_Float16)p[1];
    return __builtin_bit_cast(unsigned int, hv);
}

__device__ __forceinline__ half2v bch2(unsigned int u) {
    return __builtin_bit_cast(half2v, u);
}

// ---------------- Kernel A: fused conv1+pool1+conv2+pool2 ----------------
__global__ __launch_bounds__(256) void conv_kernel(
    const float* __restrict__ x,     // [65536][13][10]
    const float* __restrict__ c1w,   // [16][1][3][3]
    const float* __restrict__ c1b,   // [16]
    const float* __restrict__ c2w,   // [32][16][3][3]
    const float* __restrict__ c2b,   // [32]
    _Float16* __restrict__ feat)     // [65536][192]
{
    __shared__ float w1t[9 * 16];
    __shared__ float b1s[16];
    __shared__ float w2t[16 * 9 * 32];
    __shared__ float b2s[32];
    __shared__ float xp[4][14 * 12];
    __shared__ float p1p[4][16 * 8 * 7];

    const int tid = threadIdx.x;

    for (int idx = tid; idx < 144; idx += 256) {
        int oc = idx / 9, k = idx % 9;
        w1t[k * 16 + oc] = c1w[idx];
    }
    if (tid < 16) b1s[tid] = c1b[tid];
    for (int idx = tid; idx < 4608; idx += 256) {
        int oc = idx / 144, ic = (idx / 9) % 16, k = idx % 9;
        w2t[(ic * 9 + k) * 32 + oc] = c2w[idx];
    }
    if (tid < 32) b2s[tid] = c2b[tid];

    const int w = tid >> 6;
    const int lane = tid & 63;
    const int img = blockIdx.x * 4 + w;

    for (int i = lane; i < 14 * 12; i += 64) xp[w][i] = 0.f;
    for (int i = lane; i < 16 * 8 * 7; i += 64) p1p[w][i] = 0.f;
    __syncthreads();

    const float* xin = x + (size_t)img * 130;
    for (int i = lane; i < 130; i += 64) {
        int r = i / 10, c = i % 10;
        xp[w][(r + 1) * 12 + (c + 1)] = xin[i];
    }
    __syncthreads();

    {
        const int oc = lane & 15, q = lane >> 4;
        #pragma unroll
        for (int i = 0; i < 8; i++) {
            int pos = i * 4 + q;
            if (pos < 30) {
                int ph = pos / 5, pw = pos % 5;
                float cmax = -1e30f;
                #pragma unroll
                for (int pt = 0; pt < 4; pt++) {
                    int Y = 2 * ph + (pt >> 1), X = 2 * pw + (pt & 1);
                    float s = 0.f;
                    #pragma unroll
                    for (int k = 0; k < 9; k++) {
                        int dy = k / 3, dx = k % 3;
                        s += w1t[k * 16 + oc] * xp[w][(Y + dy) * 12 + X + dx];
                    }
                    cmax = fmaxf(cmax, s);
                }
                p1p[w][(oc * 8 + ph + 1) * 7 + (pw + 1)] = fmaxf(0.f, cmax + b1s[oc]);
            }
        }
    }
    __syncthreads();

    {
        const int oc = lane & 31, pw2 = lane >> 5;
        float acc[3][4];
        #pragma unroll
        for (int a = 0; a < 3; a++)
            #pragma unroll
            for (int b = 0; b < 4; b++) acc[a][b] = 0.f;

        for (int ic = 0; ic < 16; ic++) {
            #pragma unroll
            for (int k = 0; k < 9; k++) {
                int dy = k / 3, dx = k % 3;
                float wv = w2t[(ic * 9 + k) * 32 + oc];
                #pragma unroll
                for (int ph2 = 0; ph2 < 3; ph2++) {
                    #pragma unroll
                    for (int pt = 0; pt < 4; pt++) {
                        int y = 2 * ph2 + (pt >> 1) + dy;
                        int xx = 2 * pw2 + (pt & 1) + dx;
                        acc[ph2][pt] += wv * p1p[w][(ic * 8 + y) * 7 + xx];
                    }
                }
            }
        }
        float bias = b2s[oc];
        _Float16* fo = feat + (size_t)img * 192;
        #pragma unroll
        for (int ph2 = 0; ph2 < 3; ph2++) {
            float m = fmaxf(fmaxf(acc[ph2][0], acc[ph2][1]),
                            fmaxf(acc[ph2][2], acc[ph2][3]));
            fo[oc * 6 + ph2 * 2 + pw2] = (_Float16)fmaxf(0.f, m + bias);
        }
    }
}

// ---------------- Kernel B: gx = feat @ W_ih^T + bias via MFMA f16 ----------
// M=65536, N=1024, K=192. Tile 64Mx64N, full K staged (pad rows to 400 B).
// 4 waves: wave w owns m-subtile 16w x all 4 n-subtiles. mfma_f32_16x16x32_f16.
// Frag layout: A lane-> [m=lane&15][k=(lane>>4)*8+i]; B same with n; D col=lane&15,
// row=(lane>>4)*4+i (m89-verified).
__global__ __launch_bounds__(256) void gemm_gx_kernel(
    const _Float16* __restrict__ feat,  // [65536][192]
    const float* __restrict__ Wih,      // [1024][192]
    const float* __restrict__ bih,
    const float* __restrict__ bhh,
    _Float16* __restrict__ gx)          // [65536][1024]
{
    __shared__ uint4 As4[64][25];   // 25.6 KB, row stride 400 B
    __shared__ uint4 Bs4[64][25];   // 25.6 KB

    const int tid = threadIdx.x;
    const int n0 = blockIdx.x * 64;
    const int m0 = blockIdx.y * 64;

    // stage A (feat, f16): 64 rows x 24 uint4
    #pragma unroll
    for (int it = 0; it < 6; it++) {
        int q = tid + it * 256;
        int m = q / 24, c = q % 24;
        As4[m][c] = *(const uint4*)(feat + (size_t)(m0 + m) * 192 + c * 8);
    }
    // stage B (Wih, f32 -> f16): 64 rows x 96 uint
    unsigned int* Bu = (unsigned int*)Bs4;
    #pragma unroll
    for (int it = 0; it < 24; it++) {
        int q = tid + it * 256;
        int n = q / 96, p = q % 96;
        Bu[n * 100 + p] = packf2(Wih + (size_t)(n0 + n) * 192 + 2 * p);
    }
    __syncthreads();

    const int wv = tid >> 6;
    const int lane = tid & 63;
    const int lm = lane & 15;        // m (A) / n (B) within frag
    const int lk = lane >> 4;        // k-chunk

    f32x4 acc[4] = {{0.f, 0.f, 0.f, 0.f}, {0.f, 0.f, 0.f, 0.f},
                    {0.f, 0.f, 0.f, 0.f}, {0.f, 0.f, 0.f, 0.f}};

    #pragma unroll
    for (int ks = 0; ks < 6; ks++) {         // k0 = ks*32, uint4 idx = ks*4 + lk
        f16x8 a = __builtin_bit_cast(f16x8, As4[wv * 16 + lm][ks * 4 + lk]);
        #pragma unroll
        for (int j = 0; j < 4; j++) {
            f16x8 b = __builtin_bit_cast(f16x8, Bs4[j * 16 + lm][ks * 4 + lk]);
            acc[j] = __builtin_amdgcn_mfma_f32_16x16x32_f16(a, b, acc[j], 0, 0, 0);
        }
    }

    #pragma unroll
    for (int j = 0; j < 4; j++) {
        int n = n0 + j * 16 + lm;
        float bias = bih[n] + bhh[n];
        #pragma unroll
        for (int i = 0; i < 4; i++) {
            int m = m0 + wv * 16 + lk * 4 + i;
            gx[(size_t)m * 1024 + n] = (_Float16)(acc[j][i] + bias);
        }
    }
}

// ---------------- Kernel C: 512-step LSTM + classifier ----------------
// 128 blocks x 512 threads, pinned at exactly 2 waves/EU (VGPR cap 256, no spill).
// Thread t owns gate rows r0=t, r1=t+512. W_hh f16: pairs 0..91 in regs (184 VGPR),
// pairs 92..127 in LDS as uint4 [9][1024] (consecutive-lane b128, conflict-free).
__global__ __attribute__((amdgpu_flat_work_group_size(512, 512), amdgpu_waves_per_eu(2, 2)))
void lstm_kernel(
    const _Float16* __restrict__ gx, // [128][512][1024]
    const float* __restrict__ Whh,   // [1024][256]
    const float* __restrict__ clsw,  // [64][256]
    const float* __restrict__ clsb,  // [64]
    float* __restrict__ out)         // [128][64]
{
    __shared__ uint4 wl4[9][1024];                     // 144 KB: pairs 92..127
    __shared__ __align__(16) _Float16 hbuf[2][256];    // 1 KB
    __shared__ float hfin[256];                        // 1 KB
    __shared__ float xg[512];                          // 2 KB (f, o exchange)

    const int t = threadIdx.x;
    const int b = blockIdx.x;
    const int r0 = t, r1 = t + 512;

    const float* w0 = Whh + (size_t)r0 * 256;
    const float* w1 = Whh + (size_t)r1 * 256;

    half2v wr0[92], wr1[92];
    #pragma unroll
    for (int p = 0; p < 92; p++) {
        wr0[p] = bch2(packf2(&w0[2 * p]));
        wr1[p] = bch2(packf2(&w1[2 * p]));
    }
    #pragma unroll
    for (int ch = 0; ch < 9; ch++) {
        uint4 v0, v1;
        v0.x = packf2(&w0[184 + 8 * ch + 0]);
        v0.y = packf2(&w0[184 + 8 * ch + 2]);
        v0.z = packf2(&w0[184 + 8 * ch + 4]);
        v0.w = packf2(&w0[184 + 8 * ch + 6]);
        v1.x = packf2(&w1[184 + 8 * ch + 0]);
        v1.y = packf2(&w1[184 + 8 * ch + 2]);
        v1.z = packf2(&w1[184 + 8 * ch + 4]);
        v1.w = packf2(&w1[184 + 8 * ch + 6]);
        wl4[ch][r0] = v0;
        wl4[ch][r1] = v1;
    }
    if (t < 256) hbuf[0][t] = (_Float16)0.f;
    __syncthreads();

    float c = 0.f;
    int cur = 0;
    const _Float16* gxb = gx + (size_t)b * 512 * 1024;
    float ga = (float)gxb[r0];
    float gb = (float)gxb[r1];

    for (int step = 0; step < 512; step++) {
        const _Float16* gxn = gxb + (size_t)((step + 1) & 511) * 1024;
        _Float16 na = gxn[r0];
        _Float16 nb = gxn[r1];

        float acc0 = ga, acc1 = gb;
        const unsigned int* hp = (const unsigned int*)&hbuf[cur][0];

        // register-resident pairs 0..91 (h[0..183])
        #pragma unroll
        for (int ch = 0; ch < 23; ch++) {
            uint4 hv = *(const uint4*)(hp + ch * 4);
            unsigned int hw[4] = {hv.x, hv.y, hv.z, hv.w};
            #pragma unroll
            for (int j = 0; j < 4; j++) {
                half2v h2 = bch2(hw[j]);
                acc0 = dot2f16(wr0[ch * 4 + j], h2, acc0);
                acc1 = dot2f16(wr1[ch * 4 + j], h2, acc1);
            }
        }
        // LDS-resident pairs 92..127 (h[184..255]) as b128 reads
        #pragma unroll
        for (int ch = 0; ch < 9; ch++) {
            uint4 hv = *(const uint4*)(hp + 92 + 4 * ch);
            uint4 u0 = wl4[ch][r0];
            uint4 u1 = wl4[ch][r1];
            acc0 = dot2f16(bch2(u0.x), bch2(hv.x), acc0);
            acc0 = dot2f16(bch2(u0.y), bch2(hv.y), acc0);
            acc0 = dot2f16(bch2(u0.z), bch2(hv.z), acc0);
            acc0 = dot2f16(bch2(u0.w), bch2(hv.w), acc0);
            acc1 = dot2f16(bch2(u1.x), bch2(hv.x), acc1);
            acc1 = dot2f16(bch2(u1.y), bch2(hv.y), acc1);
            acc1 = dot2f16(bch2(u1.z), bch2(hv.z), acc1);
            acc1 = dot2f16(bch2(u1.w), bch2(hv.w), acc1);
        }

        if (t >= 256) {           // acc0 = f_j, acc1 = o_j for j = t-256
            xg[t - 256] = acc0;
            xg[t] = acc1;
        }
        __syncthreads();
        if (t < 256) {            // acc0 = i_j, acc1 = g_j for j = t
            float i_ = 1.f / (1.f + __expf(-acc0));
            float g_ = 1.f - 2.f / (__expf(2.f * acc1) + 1.f);
            float f_ = 1.f / (1.f + __expf(-xg[t]));
            float o_ = 1.f / (1.f + __expf(-xg[t + 256]));
            c = f_ * c + i_ * g_;
            float th = 1.f - 2.f / (__expf(2.f * c) + 1.f);
            float h = o_ * th;
            hbuf[cur ^ 1][t] = (_Float16)h;
            if (step == 511) hfin[t] = h;
        }
        __syncthreads();
        cur ^= 1;
        ga = (float)na;
        gb = (float)nb;
    }

    if (t < 64) {
        const float* wrow = clsw + t * 256;
        float s = clsb[t];
        for (int k = 0; k < 256; k++) s += wrow[k] * hfin[k];
        out[b * 64 + t] = s;
    }
}

extern "C" void kernel_launch(void* const* d_in, const int* in_sizes, int n_in,
                              void* d_out, int out_size, void* d_ws, size_t ws_size,
                              hipStream_t stream) {
    const float* x    = (const float*)d_in[0];
    const float* c1w  = (const float*)d_in[1];
    const float* c1b  = (const float*)d_in[2];
    const float* c2w  = (const float*)d_in[3];
    const float* c2b  = (const float*)d_in[4];
    const float* Wih  = (const float*)d_in[5];
    const float* bih  = (const float*)d_in[6];
    const float* Whh  = (const float*)d_in[7];
    const float* bhh  = (const float*)d_in[8];
    const float* clsw = (const float*)d_in[9];
    const float* clsb = (const float*)d_in[10];

    _Float16* feat = (_Float16*)d_ws;                   // 65536*192*2B = 25.2 MB
    _Float16* gx   = feat + (size_t)65536 * 192;        // 65536*1024*2B = 134.2 MB
    float* outp = (float*)d_out;

    hipLaunchKernelGGL(conv_kernel, dim3(16384), dim3(256), 0, stream,
                       x, c1w, c1b, c2w, c2b, feat);
    hipLaunchKernelGGL(gemm_gx_kernel, dim3(16, 1024), dim3(256), 0, stream,
                       feat, Wih, bih, bhh, gx);
    hipLaunchKernelGGL(lstm_kernel, dim3(128), dim3(512), 0, stream,
                       gx, Whh, clsw, clsb, outp);
}